// Round 2
// baseline (30011.780 us; speedup 1.0000x reference)
//
#include <hip/hip_runtime.h>
#include <stdint.h>
#include <math.h>

// ---------------------------------------------------------------------------
// Encoder: 2-layer bidirectional GRU, B=64 T=256 H=1024 V=128.
// Inputs auto-detected fp32 vs bf16 (detector kernel + canonicalizing preps).
// All matmuls: mfma_f32_16x16x32_bf16 with bf16x3 (hi/lo split) ~ fp32 accuracy.
// ---------------------------------------------------------------------------

#define B_  64
#define T_  256
#define H_  1024
#define G3_ 3072

typedef __attribute__((ext_vector_type(8))) __bf16 bf16x8;
typedef __attribute__((ext_vector_type(4))) float  f32x4;

union FragU { uint4 u; bf16x8 b; };

__device__ __forceinline__ float bf2f(unsigned short v) {
  return __builtin_bit_cast(float, (uint32_t)v << 16);
}
__device__ __forceinline__ unsigned short f2bf(float f) {
  uint32_t u = __builtin_bit_cast(uint32_t, f);
  u += 0x7FFFu + ((u >> 16) & 1u);   // RNE (no NaN inputs here)
  return (unsigned short)(u >> 16);
}
__device__ __forceinline__ bf16x8 ld_frag_g(const unsigned short* p) {
  FragU f; f.u = *(const uint4*)p; return f.b;
}

// ---------------------------------------------------------------------------
// dtype detector: fp32 arrays' even uint16s are random mantissa halves;
// bf16 arrays' even uint16s are samples with |v|<=1/32 (exp field <= 122).
// flag = 1 -> inputs are bf16, flag = 0 -> fp32.
// ---------------------------------------------------------------------------
__global__ void detect_dtype(const unsigned short* __restrict__ p, int* __restrict__ flag) {
  const int i = threadIdx.x;                 // 0..63
  const unsigned short v = p[2 * i];
  const int e = (v >> 7) & 0xFF;
  const unsigned long long m = __ballot(e <= 124);
  if (i == 0) *flag = (m == ~0ull) ? 1 : 0;
}

__device__ __forceinline__ float load_canon(const void* src, int i, bool isbf) {
  return isbf ? bf2f(((const unsigned short*)src)[i]) : ((const float*)src)[i];
}

// elementwise: src (either dtype) -> hi/lo bf16 split
__global__ void prep_split(const void* __restrict__ src, int n,
                           unsigned short* __restrict__ hi, unsigned short* __restrict__ lo,
                           const int* __restrict__ flag) {
  const int i = blockIdx.x * blockDim.x + threadIdx.x;
  if (i >= n) return;
  const bool isbf = (*flag != 0);
  const float f = load_canon(src, i, isbf);
  const unsigned short h = f2bf(f);
  hi[i] = h;
  lo[i] = f2bf(f - bf2f(h));
}

// elementwise: src (either dtype) -> fp32
__global__ void prep_f32(const void* __restrict__ src, int n,
                         float* __restrict__ dst, const int* __restrict__ flag) {
  const int i = blockIdx.x * blockDim.x + threadIdx.x;
  if (i >= n) return;
  const bool isbf = (*flag != 0);
  dst[i] = load_canon(src, i, isbf);
}

// ---------------------------------------------------------------------------
// One GRU time step, both directions in one launch.
// grid = (32 unit-tiles, 2 dirs), block = 256 (4 waves).
// Block computes, for units j in [j0, j0+32): the 96 Whh rows {j, 1024+j, 2048+j}
// times h (64 x 1024), then full gate math. MFMA mappings (m89/m91-verified):
//   A-frag: A[m = lane&15][k = (lane>>4)*8 + e]; B-frag: B[k][n = lane&15]
//   D: row(m) = (lane>>4)*4 + reg, col(n) = lane&15
// ---------------------------------------------------------------------------
template<int LAYER>
__global__ __launch_bounds__(256) void gru_step(
    const int*            __restrict__ x,       // (64,256) tokens
    const float*          __restrict__ Wih0f,   // L0: (2,3072,128) canonical fp32
    const float*          __restrict__ bihf,    // L0: (2,3072) fp32
    const _Float16*       __restrict__ xp1,     // L1: (2,16384,3072) fp16 (bias folded)
    const unsigned short* __restrict__ WhhH,    // (2,3072,1024) bf16 hi
    const unsigned short* __restrict__ WhhL,    // bf16 lo
    const float*          __restrict__ bhhf,    // (2,3072) fp32
    const float*          __restrict__ h_in_f,  // (2,64,1024)
    const unsigned short* __restrict__ h_in_hi,
    const unsigned short* __restrict__ h_in_lo,
    float*                __restrict__ h_out_f,
    unsigned short*       __restrict__ h_out_hi,
    unsigned short*       __restrict__ h_out_lo,
    unsigned short*       __restrict__ ys0_hi,  // L0 out: (64,256,2048) bf16 hi
    unsigned short*       __restrict__ ys0_lo,  // L0 out: bf16 lo
    void*                 __restrict__ d_out,   // L1 out: ys (64,256,2048) + hid (4,64,1024)
    const int*            __restrict__ flag,    // output dtype select
    int t)
{
  const int j0   = blockIdx.x << 5;
  const int d    = blockIdx.y;
  const int tid  = threadIdx.x;
  const int w    = tid >> 6;
  const int lane = tid & 63;
  const int quad = lane >> 4, l15 = lane & 15;
  const int t_eff = d ? (T_ - 1 - t) : t;
  const bool out_bf = (*flag != 0);

  const unsigned short* hhi = h_in_hi + (size_t)d * B_ * H_;
  const unsigned short* hlo = h_in_lo + (size_t)d * B_ * H_;

  f32x4 acc[6] = {};

  // A fragment source: h rows; wave w owns batch rows [16w,16w+16)
  const int am = (w << 4) + l15;
  const unsigned short* aph = hhi + (size_t)am * H_ + (quad << 3);
  const unsigned short* apl = hlo + (size_t)am * H_ + (quad << 3);
  // B fragment sources: col-tile ct covers n=[16ct,16ct+16) of the 96 gathered rows
  const unsigned short* bph[6];
  const unsigned short* bpl[6];
#pragma unroll
  for (int ct = 0; ct < 6; ++ct) {
    const int group = ct >> 1;
    const int u     = ((ct & 1) << 4) + l15;
    const size_t off = (size_t)d * G3_ * H_ + (size_t)(group * H_ + j0 + u) * H_ + (quad << 3);
    bph[ct] = WhhH + off;
    bpl[ct] = WhhL + off;
  }

  for (int k0 = 0; k0 < H_; k0 += 32) {
    bf16x8 ah = ld_frag_g(aph + k0);
    bf16x8 al = ld_frag_g(apl + k0);
#pragma unroll
    for (int ct = 0; ct < 6; ++ct) {
      bf16x8 bh = ld_frag_g(bph[ct] + k0);
      bf16x8 bl = ld_frag_g(bpl[ct] + k0);
      acc[ct] = __builtin_amdgcn_mfma_f32_16x16x32_bf16(ah, bh, acc[ct], 0, 0, 0);
      acc[ct] = __builtin_amdgcn_mfma_f32_16x16x32_bf16(al, bh, acc[ct], 0, 0, 0);
      acc[ct] = __builtin_amdgcn_mfma_f32_16x16x32_bf16(ah, bl, acc[ct], 0, 0, 0);
    }
  }

  // ---- epilogue: gate math for 8 (b, j) pairs per lane ----
  int toks[4];
#pragma unroll
  for (int r = 0; r < 4; ++r) {
    const int b = (w << 4) + (quad << 2) + r;
    if (LAYER == 0) toks[r] = x[b * T_ + t_eff];
  }

  float*          out_f  = (float*)d_out;
  unsigned short* out_b  = (unsigned short*)d_out;
  const size_t    HIDOFF = (size_t)B_ * T_ * 2048;   // ys elements before hid

#pragma unroll
  for (int p = 0; p < 2; ++p) {
    const int u = (p << 4) + l15;
    const int j = j0 + u;
    const size_t dj = (size_t)d * G3_ + j;
    const float bhr = bhhf[dj];
    const float bhz = bhhf[dj + H_];
    const float bhn = bhhf[dj + 2 * H_];
    float bir = 0.f, biz = 0.f, bin_ = 0.f;
    if (LAYER == 0) {
      bir  = bihf[dj];
      biz  = bihf[dj + H_];
      bin_ = bihf[dj + 2 * H_];
    }
#pragma unroll
    for (int r = 0; r < 4; ++r) {
      const int b = (w << 4) + (quad << 2) + r;
      const float gr = acc[p][r]     + bhr;
      const float gz = acc[2 + p][r] + bhz;
      const float gn = acc[4 + p][r] + bhn;
      float xr, xz, xn;
      if (LAYER == 0) {
        const int tok = toks[r];
        const float* W0 = Wih0f + (size_t)d * G3_ * 128;
        xr = W0[(size_t)j * 128 + tok]            + bir;
        xz = W0[(size_t)(j + H_) * 128 + tok]     + biz;
        xn = W0[(size_t)(j + 2 * H_) * 128 + tok] + bin_;
      } else {
        const _Float16* xp = xp1 + ((size_t)d * (B_ * T_) + b * T_ + t_eff) * G3_;
        xr = (float)xp[j]; xz = (float)xp[j + H_]; xn = (float)xp[j + 2 * H_];
      }
      const size_t hoff = ((size_t)d * B_ + b) * H_ + j;
      const float hprev = h_in_f[hoff];
      const float rg = 1.f / (1.f + expf(-(xr + gr)));
      const float zg = 1.f / (1.f + expf(-(xz + gz)));
      const float ng = tanhf(xn + rg * gn);
      const float hnew = (1.f - zg) * ng + zg * hprev;

      h_out_f[hoff] = hnew;
      const unsigned short hi = f2bf(hnew);
      const unsigned short lo = f2bf(hnew - bf2f(hi));
      h_out_hi[hoff] = hi;
      h_out_lo[hoff] = lo;

      const size_t yoff = ((size_t)b * T_ + t_eff) * 2048 + d * H_ + j;
      if (LAYER == 0) {
        ys0_hi[yoff] = hi;
        ys0_lo[yoff] = lo;
      } else {
        if (out_bf) out_b[yoff] = hi; else out_f[yoff] = hnew;
      }
      if (t == T_ - 1) {
        const size_t ho = HIDOFF + ((size_t)(LAYER * 2 + d) * B_ + b) * H_ + j;
        if (out_bf) out_b[ho] = hi; else out_f[ho] = hnew;
      }
    }
  }
}

// ---------------------------------------------------------------------------
// xp1 = ys0cat @ Wih1[d]^T + bih1[d], fp16 out.  M=16384 N=3072 K=2048, x2 dirs.
// 128x128 tile, BK=32, bf16x3 (AhBh + AlBh + AhBl) => 48 MFMA/wave/iter.
// ---------------------------------------------------------------------------
__global__ __launch_bounds__(256) void xp1_gemm(
    const unsigned short* __restrict__ Ahi,    // (16384,2048) ys0 hi
    const unsigned short* __restrict__ Alo,    // ys0 lo
    const unsigned short* __restrict__ Bhi,    // (2,3072,2048) Wih1 hi
    const unsigned short* __restrict__ Blo,    // Wih1 lo
    const float*          __restrict__ biasf,  // (2,3072) fp32
    _Float16*             __restrict__ xp1)    // (2,16384,3072)
{
  const int nt  = blockIdx.x;
  const int mt  = blockIdx.y;
  const int d   = blockIdx.z;
  const int tid = threadIdx.x;
  const int w = tid >> 6, lane = tid & 63;
  const int quad = lane >> 4, l15 = lane & 15;
  const int wm = w >> 1, wn = w & 1;

  __shared__ unsigned short sAh[128][40];  // +8 pad: 80B row stride
  __shared__ unsigned short sAl[128][40];
  __shared__ unsigned short sBh[128][40];
  __shared__ unsigned short sBl[128][40];

  const int srow = tid >> 1;
  const int scol = (tid & 1) << 4;
  const unsigned short* gAh = Ahi + (size_t)(mt * 128 + srow) * 2048 + scol;
  const unsigned short* gAl = Alo + (size_t)(mt * 128 + srow) * 2048 + scol;
  const unsigned short* gBh = Bhi + (size_t)d * G3_ * 2048
                                  + (size_t)(nt * 128 + srow) * 2048 + scol;
  const unsigned short* gBl = Blo + (size_t)d * G3_ * 2048
                                  + (size_t)(nt * 128 + srow) * 2048 + scol;

  f32x4 acc[4][4] = {};

  for (int k0 = 0; k0 < 2048; k0 += 32) {
    const uint4 a0 = *(const uint4*)(gAh + k0);
    const uint4 a1 = *(const uint4*)(gAh + k0 + 8);
    const uint4 l0 = *(const uint4*)(gAl + k0);
    const uint4 l1 = *(const uint4*)(gAl + k0 + 8);
    const uint4 b0 = *(const uint4*)(gBh + k0);
    const uint4 b1 = *(const uint4*)(gBh + k0 + 8);
    const uint4 c0 = *(const uint4*)(gBl + k0);
    const uint4 c1 = *(const uint4*)(gBl + k0 + 8);
    __syncthreads();                       // previous iter's LDS reads done
    *(uint4*)&sAh[srow][scol]     = a0;
    *(uint4*)&sAh[srow][scol + 8] = a1;
    *(uint4*)&sAl[srow][scol]     = l0;
    *(uint4*)&sAl[srow][scol + 8] = l1;
    *(uint4*)&sBh[srow][scol]     = b0;
    *(uint4*)&sBh[srow][scol + 8] = b1;
    *(uint4*)&sBl[srow][scol]     = c0;
    *(uint4*)&sBl[srow][scol + 8] = c1;
    __syncthreads();

    bf16x8 fah[4], fal[4], fbh[4], fbl[4];
#pragma unroll
    for (int i = 0; i < 4; ++i) {
      FragU fa; fa.u = *(const uint4*)&sAh[(wm << 6) + (i << 4) + l15][quad << 3]; fah[i] = fa.b;
      FragU fl; fl.u = *(const uint4*)&sAl[(wm << 6) + (i << 4) + l15][quad << 3]; fal[i] = fl.b;
      FragU fb; fb.u = *(const uint4*)&sBh[(wn << 6) + (i << 4) + l15][quad << 3]; fbh[i] = fb.b;
      FragU fc; fc.u = *(const uint4*)&sBl[(wn << 6) + (i << 4) + l15][quad << 3]; fbl[i] = fc.b;
    }
#pragma unroll
    for (int i = 0; i < 4; ++i)
#pragma unroll
      for (int jj = 0; jj < 4; ++jj) {
        acc[i][jj] = __builtin_amdgcn_mfma_f32_16x16x32_bf16(fah[i], fbh[jj], acc[i][jj], 0, 0, 0);
        acc[i][jj] = __builtin_amdgcn_mfma_f32_16x16x32_bf16(fal[i], fbh[jj], acc[i][jj], 0, 0, 0);
        acc[i][jj] = __builtin_amdgcn_mfma_f32_16x16x32_bf16(fah[i], fbl[jj], acc[i][jj], 0, 0, 0);
      }
  }

#pragma unroll
  for (int jj = 0; jj < 4; ++jj) {
    const int col = nt * 128 + (wn << 6) + (jj << 4) + l15;
    const float bias = biasf[(size_t)d * G3_ + col];
#pragma unroll
    for (int i = 0; i < 4; ++i) {
      const int m = mt * 128 + (wm << 6) + (i << 4) + (quad << 2);
      _Float16* op = xp1 + ((size_t)d * (B_ * T_) + m) * G3_ + col;
#pragma unroll
      for (int r = 0; r < 4; ++r) op[(size_t)r * G3_] = (_Float16)(acc[i][jj][r] + bias);
    }
  }
}

// ---------------------------------------------------------------------------
extern "C" void kernel_launch(void* const* d_in, const int* in_sizes, int n_in,
                              void* d_out, int out_size, void* d_ws, size_t ws_size,
                              hipStream_t stream)
{
  const int*  x    = (const int*)d_in[0];
  const void* Wih0 = d_in[1];   // (2,3072,128)
  const void* Whh0 = d_in[2];   // (2,3072,1024)
  const void* bih0 = d_in[3];   // (2,3072)
  const void* bhh0 = d_in[4];
  const void* Wih1 = d_in[5];   // (2,3072,2048)
  const void* Whh1 = d_in[6];   // (2,3072,1024)
  const void* bih1 = d_in[7];
  const void* bhh1 = d_in[8];

  // ---- workspace carve ----
  const size_t FLAG_B = 256;
  const size_t XP1_B  = (size_t)2 * B_ * T_ * G3_ * 2;    // fp16: 201,326,592
  const size_t YS_B   = (size_t)B_ * T_ * 2048 * 2;       // 67,108,864 (each)
  const size_t WHH_B  = (size_t)2 * G3_ * H_ * 2;         // 12,582,912 (each)
  const size_t WIH1_B = (size_t)2 * G3_ * 2048 * 2;       // 25,165,824 (each)
  const size_t WIH0_B = (size_t)2 * G3_ * 128 * 4;        // 3,145,728
  const size_t BIAS_B = (size_t)2 * G3_ * 4;              // 24,576 (each of 4)
  const size_t HF_B   = (size_t)2 * 2 * B_ * H_ * 4;      // 1,048,576
  const size_t HB_B   = (size_t)2 * 2 * B_ * H_ * 2;      // 524,288
  const size_t NEED = FLAG_B + XP1_B + 2 * YS_B + 4 * WHH_B + 2 * WIH1_B
                    + WIH0_B + 4 * BIAS_B + HF_B + 2 * HB_B;
  if (ws_size < NEED) return;   // diagnostic: output stays zero

  char* p = (char*)d_ws;
  int*            flag    = (int*)p;            p += FLAG_B;
  _Float16*       xp1     = (_Float16*)p;       p += XP1_B;
  unsigned short* ys0_hi  = (unsigned short*)p; p += YS_B;
  unsigned short* ys0_lo  = (unsigned short*)p; p += YS_B;
  unsigned short* Whh0H   = (unsigned short*)p; p += WHH_B;
  unsigned short* Whh0L   = (unsigned short*)p; p += WHH_B;
  unsigned short* Whh1H   = (unsigned short*)p; p += WHH_B;
  unsigned short* Whh1L   = (unsigned short*)p; p += WHH_B;
  unsigned short* Wih1H   = (unsigned short*)p; p += WIH1_B;
  unsigned short* Wih1L   = (unsigned short*)p; p += WIH1_B;
  float*          Wih0f   = (float*)p;          p += WIH0_B;
  float*          bih0f   = (float*)p;          p += BIAS_B;
  float*          bhh0f   = (float*)p;          p += BIAS_B;
  float*          bih1f   = (float*)p;          p += BIAS_B;
  float*          bhh1f   = (float*)p;          p += BIAS_B;
  char*           hbase   = p;
  float*          hf      = (float*)hbase;
  unsigned short* hhi     = (unsigned short*)(hbase + HF_B);
  unsigned short* hlo     = (unsigned short*)(hbase + HF_B + HB_B);

  const size_t HF_HALF = (size_t)2 * B_ * H_;   // elements per ping-pong slot
  const size_t HB_HALF = (size_t)2 * B_ * H_;

  // ---- dtype detect + canonicalize ----
  detect_dtype<<<1, 64, 0, stream>>>((const unsigned short*)bih0, flag);

  const int NWHH  = 2 * G3_ * H_;      // 6,291,456
  const int NWIH1 = 2 * G3_ * 2048;    // 12,582,912
  const int NWIH0 = 2 * G3_ * 128;     // 786,432
  const int NBIAS = 2 * G3_;           // 6,144
  prep_split<<<(NWHH  + 255) / 256, 256, 0, stream>>>(Whh0, NWHH,  Whh0H, Whh0L, flag);
  prep_split<<<(NWHH  + 255) / 256, 256, 0, stream>>>(Whh1, NWHH,  Whh1H, Whh1L, flag);
  prep_split<<<(NWIH1 + 255) / 256, 256, 0, stream>>>(Wih1, NWIH1, Wih1H, Wih1L, flag);
  prep_f32<<<(NWIH0 + 255) / 256, 256, 0, stream>>>(Wih0, NWIH0, Wih0f, flag);
  prep_f32<<<(NBIAS + 255) / 256, 256, 0, stream>>>(bih0, NBIAS, bih0f, flag);
  prep_f32<<<(NBIAS + 255) / 256, 256, 0, stream>>>(bhh0, NBIAS, bhh0f, flag);
  prep_f32<<<(NBIAS + 255) / 256, 256, 0, stream>>>(bih1, NBIAS, bih1f, flag);
  prep_f32<<<(NBIAS + 255) / 256, 256, 0, stream>>>(bhh1, NBIAS, bhh1f, flag);

  // ---- layer 0 scan ----
  hipMemsetAsync(hbase, 0, HF_B + 2 * HB_B, stream);
  for (int t = 0; t < T_; ++t) {
    const int pi = t & 1, po = pi ^ 1;
    gru_step<0><<<dim3(32, 2), 256, 0, stream>>>(
        x, Wih0f, bih0f, nullptr, Whh0H, Whh0L, bhh0f,
        hf + pi * HF_HALF, hhi + pi * HB_HALF, hlo + pi * HB_HALF,
        hf + po * HF_HALF, hhi + po * HB_HALF, hlo + po * HB_HALF,
        ys0_hi, ys0_lo, d_out, flag, t);
  }

  // ---- layer-1 input projection ----
  xp1_gemm<<<dim3(24, 128, 2), 256, 0, stream>>>(ys0_hi, ys0_lo, Wih1H, Wih1L, bih1f, xp1);

  // ---- layer 1 scan ----
  hipMemsetAsync(hbase, 0, HF_B + 2 * HB_B, stream);
  for (int t = 0; t < T_; ++t) {
    const int pi = t & 1, po = pi ^ 1;
    gru_step<1><<<dim3(32, 2), 256, 0, stream>>>(
        x, nullptr, nullptr, xp1, Whh1H, Whh1L, bhh1f,
        hf + pi * HF_HALF, hhi + pi * HB_HALF, hlo + pi * HB_HALF,
        hf + po * HF_HALF, hhi + po * HB_HALF, hlo + po * HB_HALF,
        nullptr, nullptr, d_out, flag, t);
  }
}

// Round 4
// 26567.526 us; speedup vs baseline: 1.1296x; 1.1296x over previous
//
#include <hip/hip_runtime.h>
#include <stdint.h>
#include <math.h>

// ---------------------------------------------------------------------------
// Encoder: 2-layer bidirectional GRU, B=64 T=256 H=1024 V=128, bf16 in/out
// (dtype auto-detected; fp32 fallback kept). Scans: ONE persistent kernel per
// layer with a hand-rolled device-scope grid barrier per timestep (plain
// launches — hipLaunchCooperativeKernel failed silently in round 3).
// Matmuls: mfma_f32_16x16x32_bf16; h carried as fp32 + hi/lo bf16 split.
// Weight-lo terms skipped when inputs are bf16 (lo == 0 exactly).
// ---------------------------------------------------------------------------

#define B_  64
#define T_  256
#define H_  1024
#define G3_ 3072
#define NBLK 128u   // scan grid: 64 unit-tiles x 2 dirs

typedef __attribute__((ext_vector_type(8))) __bf16 bf16x8;
typedef __attribute__((ext_vector_type(4))) float  f32x4;

union FragU { uint4 u; bf16x8 b; };

__device__ __forceinline__ float bf2f(unsigned short v) {
  return __builtin_bit_cast(float, (uint32_t)v << 16);
}
__device__ __forceinline__ unsigned short f2bf(float f) {
  uint32_t u = __builtin_bit_cast(uint32_t, f);
  u += 0x7FFFu + ((u >> 16) & 1u);   // RNE (no NaN inputs here)
  return (unsigned short)(u >> 16);
}
__device__ __forceinline__ bf16x8 ld_frag_g(const unsigned short* p) {
  FragU f; f.u = *(const uint4*)p; return f.b;
}

// ---------------------------------------------------------------------------
// Device-scope grid barrier (all NBLK blocks co-resident by construction).
// __syncthreads drains each wave's stores (compiler emits vmcnt(0) before
// s_barrier); tid0's __threadfence releases them to MALL; spinners use
// agent-scope atomic loads (bypass stale per-XCD L2); acquire fence after.
// ---------------------------------------------------------------------------
__device__ __forceinline__ void grid_bar(unsigned* cnt, unsigned* gen, unsigned& lg) {
  __syncthreads();
  if (threadIdx.x == 0) {
    __threadfence();
    const unsigned arrived =
        __hip_atomic_fetch_add(cnt, 1u, __ATOMIC_RELAXED, __HIP_MEMORY_SCOPE_AGENT);
    if (arrived == NBLK - 1u) {
      __hip_atomic_store(cnt, 0u, __ATOMIC_RELAXED, __HIP_MEMORY_SCOPE_AGENT);
      __hip_atomic_fetch_add(gen, 1u, __ATOMIC_RELEASE, __HIP_MEMORY_SCOPE_AGENT);
    } else {
      unsigned spins = 0;
      while (__hip_atomic_load(gen, __ATOMIC_RELAXED, __HIP_MEMORY_SCOPE_AGENT) == lg) {
        __builtin_amdgcn_s_sleep(2);
        if (++spins > (1u << 21)) break;   // safety valve (never hit when co-resident)
      }
    }
  }
  __syncthreads();
  __threadfence();
  ++lg;
}

// ---------------------------------------------------------------------------
// dtype detector: fp32 arrays' even uint16s are random mantissa halves;
// bf16 arrays' even uint16s are samples with |v|<=1/32 (exp field <= 122).
// ---------------------------------------------------------------------------
__global__ void detect_dtype(const unsigned short* __restrict__ p, int* __restrict__ flag) {
  const int i = threadIdx.x;                 // 0..63
  const unsigned short v = p[2 * i];
  const int e = (v >> 7) & 0xFF;
  const unsigned long long m = __ballot(e <= 124);
  if (i == 0) *flag = (m == ~0ull) ? 1 : 0;
}

__device__ __forceinline__ float load_canon(const void* src, int i, bool isbf) {
  return isbf ? bf2f(((const unsigned short*)src)[i]) : ((const float*)src)[i];
}

__global__ void prep_split(const void* __restrict__ src, int n,
                           unsigned short* __restrict__ hi, unsigned short* __restrict__ lo,
                           const int* __restrict__ flag) {
  const int i = blockIdx.x * blockDim.x + threadIdx.x;
  if (i >= n) return;
  const bool isbf = (*flag != 0);
  const float f = load_canon(src, i, isbf);
  const unsigned short h = f2bf(f);
  hi[i] = h;
  lo[i] = f2bf(f - bf2f(h));
}

__global__ void prep_f32(const void* __restrict__ src, int n,
                         float* __restrict__ dst, const int* __restrict__ flag) {
  const int i = blockIdx.x * blockDim.x + threadIdx.x;
  if (i >= n) return;
  const bool isbf = (*flag != 0);
  dst[i] = load_canon(src, i, isbf);
}

// ---------------------------------------------------------------------------
// Persistent GRU scan: one launch per layer, both directions.
// grid = (64 unit-tiles of 16, 2 dirs) = 128 blocks, block = 256 (4 waves).
// Wave w handles batch rows [16w,16w+16); 3 accumulators = r/z/n gates for
// units j0..j0+15. Hand-rolled grid barrier per timestep.
// MFMA maps (m89/m91): A[m=lane&15][k=(lane>>4)*8+e]; B[n=lane&15][k];
// D: row m=(lane>>4)*4+reg, col n=lane&15.
// ---------------------------------------------------------------------------
template<int LAYER>
__global__ __launch_bounds__(256) void gru_scan(
    const int*            __restrict__ x,       // (64,256) tokens
    const float*          __restrict__ Wih0f,   // L0: (2,3072,128) fp32
    const float*          __restrict__ bihf,    // L0: (2,3072) fp32
    const _Float16*       __restrict__ xp1,     // L1: (2,16384,3072) fp16
    const unsigned short* __restrict__ WhhH,    // (2,3072,1024) bf16 hi
    const unsigned short* __restrict__ WhhL,    // bf16 lo
    const float*          __restrict__ bhhf,    // (2,3072) fp32
    float*                __restrict__ hf,      // [2 slots][2,64,1024] fp32
    unsigned short*       __restrict__ hhi,
    unsigned short*       __restrict__ hlo,
    unsigned short*       __restrict__ ys0_hi,  // L0 out: (64,256,2048)
    unsigned short*       __restrict__ ys0_lo,
    void*                 __restrict__ d_out,   // L1 out + hiddens
    const int*            __restrict__ flag,
    unsigned*             __restrict__ bar_cnt,
    unsigned*             __restrict__ bar_gen)
{
  const int j0   = blockIdx.x << 4;       // unit tile base (16 units)
  const int d    = blockIdx.y;
  const int tid  = threadIdx.x;
  const int w    = tid >> 6;
  const int lane = tid & 63;
  const int quad = lane >> 4, l15 = lane & 15;
  const bool out_bf = (*flag != 0);
  const bool wlo    = (*flag == 0);       // weight-lo terms only for fp32 inputs

  const int j = j0 + l15;                 // this lane's unit
  const size_t HF_HALF = (size_t)2 * B_ * H_;

  // ---- loop-invariant pointers ----
  const int am = (w << 4) + l15;          // A-frag batch row
  const unsigned short* aphS[2], *aplS[2];
  const float* hinS[2];
  float* houtS[2];
  unsigned short *hhiS[2], *hloS[2];
#pragma unroll
  for (int s = 0; s < 2; ++s) {
    aphS[s] = hhi + s * HF_HALF + ((size_t)d * B_ + am) * H_ + (quad << 3);
    aplS[s] = hlo + s * HF_HALF + ((size_t)d * B_ + am) * H_ + (quad << 3);
    hinS[s]  = hf  + s * HF_HALF + (size_t)d * B_ * H_;
    houtS[s] = hf  + s * HF_HALF + (size_t)d * B_ * H_;
    hhiS[s]  = hhi + s * HF_HALF + (size_t)d * B_ * H_;
    hloS[s]  = hlo + s * HF_HALF + (size_t)d * B_ * H_;
  }

  const unsigned short* bph[3];
  const unsigned short* bpl[3];
#pragma unroll
  for (int g = 0; g < 3; ++g) {
    const size_t off = (size_t)d * G3_ * H_ + (size_t)(g * H_ + j0 + l15) * H_ + (quad << 3);
    bph[g] = WhhH + off;
    bpl[g] = WhhL + off;
  }

  const size_t dj = (size_t)d * G3_ + j;
  const float bhr = bhhf[dj];
  const float bhz = bhhf[dj + H_];
  const float bhn = bhhf[dj + 2 * H_];
  float bir = 0.f, biz = 0.f, bin_ = 0.f;
  const float *rowR = nullptr, *rowZ = nullptr, *rowN = nullptr;
  if (LAYER == 0) {
    bir  = bihf[dj];
    biz  = bihf[dj + H_];
    bin_ = bihf[dj + 2 * H_];
    const float* W0 = Wih0f + (size_t)d * G3_ * 128;
    rowR = W0 + (size_t)j * 128;
    rowZ = W0 + (size_t)(j + H_) * 128;
    rowN = W0 + (size_t)(j + 2 * H_) * 128;
  }
  const _Float16* xpd = (LAYER == 1) ? (xp1 + (size_t)d * (B_ * T_) * G3_) : nullptr;

  float*          out_f  = (float*)d_out;
  unsigned short* out_b  = (unsigned short*)d_out;
  const size_t    HIDOFF = (size_t)B_ * T_ * 2048;

  unsigned lg = 0;   // local barrier generation

  for (int t = 0; t < T_; ++t) {
    const int t_eff = d ? (T_ - 1 - t) : t;
    const int pi = t & 1, po = pi ^ 1;

    const unsigned short* aph = aphS[pi];
    const unsigned short* apl = aplS[pi];

    f32x4 acc[3] = {};
    if (wlo) {
      for (int k0 = 0; k0 < H_; k0 += 32) {
        bf16x8 ah = ld_frag_g(aph + k0);
        bf16x8 al = ld_frag_g(apl + k0);
#pragma unroll
        for (int g = 0; g < 3; ++g) {
          bf16x8 bh = ld_frag_g(bph[g] + k0);
          bf16x8 bl = ld_frag_g(bpl[g] + k0);
          acc[g] = __builtin_amdgcn_mfma_f32_16x16x32_bf16(ah, bh, acc[g], 0, 0, 0);
          acc[g] = __builtin_amdgcn_mfma_f32_16x16x32_bf16(al, bh, acc[g], 0, 0, 0);
          acc[g] = __builtin_amdgcn_mfma_f32_16x16x32_bf16(ah, bl, acc[g], 0, 0, 0);
        }
      }
    } else {
      for (int k0 = 0; k0 < H_; k0 += 32) {
        bf16x8 ah = ld_frag_g(aph + k0);
        bf16x8 al = ld_frag_g(apl + k0);
#pragma unroll
        for (int g = 0; g < 3; ++g) {
          bf16x8 bh = ld_frag_g(bph[g] + k0);
          acc[g] = __builtin_amdgcn_mfma_f32_16x16x32_bf16(ah, bh, acc[g], 0, 0, 0);
          acc[g] = __builtin_amdgcn_mfma_f32_16x16x32_bf16(al, bh, acc[g], 0, 0, 0);
        }
      }
    }

    // ---- gate math: 4 (b, j) pairs per lane ----
#pragma unroll
    for (int r = 0; r < 4; ++r) {
      const int b = (w << 4) + (quad << 2) + r;
      float xr, xz, xn;
      if (LAYER == 0) {
        const int tok = x[b * T_ + t_eff];
        xr = rowR[tok] + bir;
        xz = rowZ[tok] + biz;
        xn = rowN[tok] + bin_;
      } else {
        const _Float16* xp = xpd + ((size_t)b * T_ + t_eff) * G3_;
        xr = (float)xp[j]; xz = (float)xp[j + H_]; xn = (float)xp[j + 2 * H_];
      }
      const float gr = acc[0][r] + bhr;
      const float gz = acc[1][r] + bhz;
      const float gn = acc[2][r] + bhn;

      const size_t ho = (size_t)b * H_ + j;
      const float hprev = hinS[pi][ho];
      const float rg = 1.f / (1.f + expf(-(xr + gr)));
      const float zg = 1.f / (1.f + expf(-(xz + gz)));
      const float ng = tanhf(xn + rg * gn);
      const float hnew = (1.f - zg) * ng + zg * hprev;

      houtS[po][ho] = hnew;
      const unsigned short hi = f2bf(hnew);
      const unsigned short lo = f2bf(hnew - bf2f(hi));
      hhiS[po][ho] = hi;
      hloS[po][ho] = lo;

      const size_t yoff = ((size_t)b * T_ + t_eff) * 2048 + d * H_ + j;
      if (LAYER == 0) {
        ys0_hi[yoff] = hi;
        ys0_lo[yoff] = lo;
      } else {
        if (out_bf) out_b[yoff] = hi; else out_f[yoff] = hnew;
      }
      if (t == T_ - 1) {
        const size_t hh = HIDOFF + ((size_t)(LAYER * 2 + d) * B_ + b) * H_ + j;
        if (out_bf) out_b[hh] = hi; else out_f[hh] = hnew;
      }
    }

    grid_bar(bar_cnt, bar_gen, lg);
  }
}

// ---------------------------------------------------------------------------
// xp1 = ys0cat @ Wih1[d]^T + bih1[d], fp16 out.  M=16384 N=3072 K=2048, x2 dirs.
// 128x128 tile, BK=32; A hi/lo always, B lo only when inputs were fp32.
// ---------------------------------------------------------------------------
__global__ __launch_bounds__(256) void xp1_gemm(
    const unsigned short* __restrict__ Ahi,    // (16384,2048) ys0 hi
    const unsigned short* __restrict__ Alo,    // ys0 lo
    const unsigned short* __restrict__ Bhi,    // (2,3072,2048) Wih1 hi
    const unsigned short* __restrict__ Blo,    // Wih1 lo
    const float*          __restrict__ biasf,  // (2,3072) fp32
    _Float16*             __restrict__ xp1,    // (2,16384,3072)
    const int*            __restrict__ flag)
{
  const int nt  = blockIdx.x;
  const int mt  = blockIdx.y;
  const int d   = blockIdx.z;
  const int tid = threadIdx.x;
  const int w = tid >> 6, lane = tid & 63;
  const int quad = lane >> 4, l15 = lane & 15;
  const int wm = w >> 1, wn = w & 1;
  const bool wlo = (*flag == 0);

  __shared__ unsigned short sAh[128][40];  // +8 pad: 80B row stride
  __shared__ unsigned short sAl[128][40];
  __shared__ unsigned short sBh[128][40];
  __shared__ unsigned short sBl[128][40];

  const int srow = tid >> 1;
  const int scol = (tid & 1) << 4;
  const unsigned short* gAh = Ahi + (size_t)(mt * 128 + srow) * 2048 + scol;
  const unsigned short* gAl = Alo + (size_t)(mt * 128 + srow) * 2048 + scol;
  const unsigned short* gBh = Bhi + (size_t)d * G3_ * 2048
                                  + (size_t)(nt * 128 + srow) * 2048 + scol;
  const unsigned short* gBl = Blo + (size_t)d * G3_ * 2048
                                  + (size_t)(nt * 128 + srow) * 2048 + scol;

  f32x4 acc[4][4] = {};

  for (int k0 = 0; k0 < 2048; k0 += 32) {
    const uint4 a0 = *(const uint4*)(gAh + k0);
    const uint4 a1 = *(const uint4*)(gAh + k0 + 8);
    const uint4 l0 = *(const uint4*)(gAl + k0);
    const uint4 l1 = *(const uint4*)(gAl + k0 + 8);
    const uint4 b0 = *(const uint4*)(gBh + k0);
    const uint4 b1 = *(const uint4*)(gBh + k0 + 8);
    uint4 c0, c1;
    if (wlo) { c0 = *(const uint4*)(gBl + k0); c1 = *(const uint4*)(gBl + k0 + 8); }
    __syncthreads();                       // previous iter's LDS reads done
    *(uint4*)&sAh[srow][scol]     = a0;
    *(uint4*)&sAh[srow][scol + 8] = a1;
    *(uint4*)&sAl[srow][scol]     = l0;
    *(uint4*)&sAl[srow][scol + 8] = l1;
    *(uint4*)&sBh[srow][scol]     = b0;
    *(uint4*)&sBh[srow][scol + 8] = b1;
    if (wlo) {
      *(uint4*)&sBl[srow][scol]     = c0;
      *(uint4*)&sBl[srow][scol + 8] = c1;
    }
    __syncthreads();

    bf16x8 fah[4], fal[4], fbh[4];
#pragma unroll
    for (int i = 0; i < 4; ++i) {
      FragU fa; fa.u = *(const uint4*)&sAh[(wm << 6) + (i << 4) + l15][quad << 3]; fah[i] = fa.b;
      FragU fl; fl.u = *(const uint4*)&sAl[(wm << 6) + (i << 4) + l15][quad << 3]; fal[i] = fl.b;
      FragU fb; fb.u = *(const uint4*)&sBh[(wn << 6) + (i << 4) + l15][quad << 3]; fbh[i] = fb.b;
    }
#pragma unroll
    for (int i = 0; i < 4; ++i)
#pragma unroll
      for (int jj = 0; jj < 4; ++jj) {
        acc[i][jj] = __builtin_amdgcn_mfma_f32_16x16x32_bf16(fah[i], fbh[jj], acc[i][jj], 0, 0, 0);
        acc[i][jj] = __builtin_amdgcn_mfma_f32_16x16x32_bf16(fal[i], fbh[jj], acc[i][jj], 0, 0, 0);
      }
    if (wlo) {
#pragma unroll
      for (int jj = 0; jj < 4; ++jj) {
        FragU fc; fc.u = *(const uint4*)&sBl[(wn << 6) + (jj << 4) + l15][quad << 3];
#pragma unroll
        for (int i = 0; i < 4; ++i)
          acc[i][jj] = __builtin_amdgcn_mfma_f32_16x16x32_bf16(fah[i], fc.b, acc[i][jj], 0, 0, 0);
      }
    }
  }

#pragma unroll
  for (int jj = 0; jj < 4; ++jj) {
    const int col = nt * 128 + (wn << 6) + (jj << 4) + l15;
    const float bias = biasf[(size_t)d * G3_ + col];
#pragma unroll
    for (int i = 0; i < 4; ++i) {
      const int m = mt * 128 + (wm << 6) + (i << 4) + (quad << 2);
      _Float16* op = xp1 + ((size_t)d * (B_ * T_) + m) * G3_ + col;
#pragma unroll
      for (int r = 0; r < 4; ++r) op[(size_t)r * G3_] = (_Float16)(acc[i][jj][r] + bias);
    }
  }
}

// ---------------------------------------------------------------------------
extern "C" void kernel_launch(void* const* d_in, const int* in_sizes, int n_in,
                              void* d_out, int out_size, void* d_ws, size_t ws_size,
                              hipStream_t stream)
{
  const int*  x    = (const int*)d_in[0];
  const void* Wih0 = d_in[1];   // (2,3072,128)
  const void* Whh0 = d_in[2];   // (2,3072,1024)
  const void* bih0 = d_in[3];   // (2,3072)
  const void* bhh0 = d_in[4];
  const void* Wih1 = d_in[5];   // (2,3072,2048)
  const void* Whh1 = d_in[6];   // (2,3072,1024)
  const void* bih1 = d_in[7];
  const void* bhh1 = d_in[8];

  // ---- workspace carve ----
  const size_t FLAG_B = 256;
  const size_t XP1_B  = (size_t)2 * B_ * T_ * G3_ * 2;    // fp16: 201,326,592
  const size_t YS_B   = (size_t)B_ * T_ * 2048 * 2;       // 67,108,864 (each)
  const size_t WHH_B  = (size_t)2 * G3_ * H_ * 2;         // 12,582,912 (each)
  const size_t WIH1_B = (size_t)2 * G3_ * 2048 * 2;       // 25,165,824 (each)
  const size_t WIH0_B = (size_t)2 * G3_ * 128 * 4;        // 3,145,728
  const size_t BIAS_B = (size_t)2 * G3_ * 4;              // 24,576 (each of 4)
  const size_t HF_B   = (size_t)2 * 2 * B_ * H_ * 4;      // 1,048,576
  const size_t HB_B   = (size_t)2 * 2 * B_ * H_ * 2;      // 524,288
  const size_t BAR_B  = 256;
  const size_t NEED = FLAG_B + XP1_B + 2 * YS_B + 4 * WHH_B + 2 * WIH1_B
                    + WIH0_B + 4 * BIAS_B + HF_B + 2 * HB_B + BAR_B;
  if (ws_size < NEED) return;   // diagnostic: output stays zero

  char* p = (char*)d_ws;
  int*            flag    = (int*)p;            p += FLAG_B;
  _Float16*       xp1     = (_Float16*)p;       p += XP1_B;
  unsigned short* ys0_hi  = (unsigned short*)p; p += YS_B;
  unsigned short* ys0_lo  = (unsigned short*)p; p += YS_B;
  unsigned short* Whh0H   = (unsigned short*)p; p += WHH_B;
  unsigned short* Whh0L   = (unsigned short*)p; p += WHH_B;
  unsigned short* Whh1H   = (unsigned short*)p; p += WHH_B;
  unsigned short* Whh1L   = (unsigned short*)p; p += WHH_B;
  unsigned short* Wih1H   = (unsigned short*)p; p += WIH1_B;
  unsigned short* Wih1L   = (unsigned short*)p; p += WIH1_B;
  float*          Wih0f   = (float*)p;          p += WIH0_B;
  float*          bih0f   = (float*)p;          p += BIAS_B;
  float*          bhh0f   = (float*)p;          p += BIAS_B;
  float*          bih1f   = (float*)p;          p += BIAS_B;
  float*          bhh1f   = (float*)p;          p += BIAS_B;
  char*           hbase   = p;
  float*          hf      = (float*)hbase;
  unsigned short* hhi     = (unsigned short*)(hbase + HF_B);
  unsigned short* hlo     = (unsigned short*)(hbase + HF_B + HB_B);
  unsigned*       bar_cnt = (unsigned*)(hbase + HF_B + 2 * HB_B);
  unsigned*       bar_gen = bar_cnt + 1;

  // ---- dtype detect + canonicalize ----
  detect_dtype<<<1, 64, 0, stream>>>((const unsigned short*)bih0, flag);

  const int NWHH  = 2 * G3_ * H_;
  const int NWIH1 = 2 * G3_ * 2048;
  const int NWIH0 = 2 * G3_ * 128;
  const int NBIAS = 2 * G3_;
  prep_split<<<(NWHH  + 255) / 256, 256, 0, stream>>>(Whh0, NWHH,  Whh0H, Whh0L, flag);
  prep_split<<<(NWHH  + 255) / 256, 256, 0, stream>>>(Whh1, NWHH,  Whh1H, Whh1L, flag);
  prep_split<<<(NWIH1 + 255) / 256, 256, 0, stream>>>(Wih1, NWIH1, Wih1H, Wih1L, flag);
  prep_f32<<<(NWIH0 + 255) / 256, 256, 0, stream>>>(Wih0, NWIH0, Wih0f, flag);
  prep_f32<<<(NBIAS + 255) / 256, 256, 0, stream>>>(bih0, NBIAS, bih0f, flag);
  prep_f32<<<(NBIAS + 255) / 256, 256, 0, stream>>>(bhh0, NBIAS, bhh0f, flag);
  prep_f32<<<(NBIAS + 255) / 256, 256, 0, stream>>>(bih1, NBIAS, bih1f, flag);
  prep_f32<<<(NBIAS + 255) / 256, 256, 0, stream>>>(bhh1, NBIAS, bhh1f, flag);

  // ---- layer 0 scan (persistent, hand-rolled grid barrier) ----
  hipMemsetAsync(hbase, 0, HF_B + 2 * HB_B + BAR_B, stream);
  gru_scan<0><<<dim3(64, 2), 256, 0, stream>>>(
      x, Wih0f, bih0f, nullptr, Whh0H, Whh0L, bhh0f,
      hf, hhi, hlo, ys0_hi, ys0_lo, d_out, flag, bar_cnt, bar_gen);

  // ---- layer-1 input projection ----
  xp1_gemm<<<dim3(24, 128, 2), 256, 0, stream>>>(ys0_hi, ys0_lo, Wih1H, Wih1L, bih1f, xp1, flag);

  // ---- layer 1 scan ----
  hipMemsetAsync(hbase, 0, HF_B + 2 * HB_B + BAR_B, stream);
  gru_scan<1><<<dim3(64, 2), 256, 0, stream>>>(
      x, nullptr, nullptr, xp1, Whh1H, Whh1L, bhh1f,
      hf, hhi, hlo, nullptr, nullptr, d_out, flag, bar_cnt, bar_gen);
}